// Round 1
// baseline (585.567 us; speedup 1.0000x reference)
//
#include <hip/hip_runtime.h>

// Problem constants: B=2, L=256, D=512, H=8, dk=64
#define L_SEQ 256
#define D_MODEL 512
#define N_HEADS 8
#define DK 64
#define N_BATCH 2
#define BH (N_BATCH * N_HEADS)   // 16

// ---------------------------------------------------------------------------
// NT GEMM for the 512x512x512 projections. out[r,c] = X[r,:].W[c,:] + bias[c]
// grid.z selects (X,W,bias,out) triple so all of Q/K/V run in ONE launch.
// 32x32 tile, 2x2 register tile per thread, float4 (b128) LDS reads.
// ---------------------------------------------------------------------------
__global__ __launch_bounds__(256) void proj_gemm(
    const float* __restrict__ X0, const float* __restrict__ X1, const float* __restrict__ X2,
    const float* __restrict__ W0, const float* __restrict__ W1, const float* __restrict__ W2,
    const float* __restrict__ B0, const float* __restrict__ B1, const float* __restrict__ B2,
    float* __restrict__ O0, float* __restrict__ O1, float* __restrict__ O2,
    int split_heads)
{
    const int z = blockIdx.z;
    const float* X    = (z == 0) ? X0 : (z == 1) ? X1 : X2;
    const float* W    = (z == 0) ? W0 : (z == 1) ? W1 : W2;
    const float* bias = (z == 0) ? B0 : (z == 1) ? B1 : B2;
    float* out        = (z == 0) ? O0 : (z == 1) ? O1 : O2;

    __shared__ float Xs[32][36];
    __shared__ float Ws[32][36];

    const int t = threadIdx.x;
    const int row0 = blockIdx.x * 32;
    const int col0 = blockIdx.y * 32;
    const int lr = t >> 3;          // 0..31 (staging row)
    const int lc = (t & 7) << 2;    // 0..28 (staging col, float4)
    const int r0 = (t >> 4) * 2;    // output rows r0, r0+1
    const int c0 = (t & 15) * 2;    // output cols c0, c0+1

    float a00 = 0.f, a01 = 0.f, a10 = 0.f, a11 = 0.f;

    for (int k0 = 0; k0 < 512; k0 += 32) {
        __syncthreads();
        *(float4*)&Xs[lr][lc] = *(const float4*)&X[(size_t)(row0 + lr) * 512 + k0 + lc];
        *(float4*)&Ws[lr][lc] = *(const float4*)&W[(size_t)(col0 + lr) * 512 + k0 + lc];
        __syncthreads();
#pragma unroll
        for (int kk = 0; kk < 32; kk += 4) {
            const float4 x0 = *(const float4*)&Xs[r0][kk];
            const float4 x1 = *(const float4*)&Xs[r0 + 1][kk];
            const float4 w0 = *(const float4*)&Ws[c0][kk];
            const float4 w1 = *(const float4*)&Ws[c0 + 1][kk];
            a00 = fmaf(x0.x, w0.x, fmaf(x0.y, w0.y, fmaf(x0.z, w0.z, fmaf(x0.w, w0.w, a00))));
            a01 = fmaf(x0.x, w1.x, fmaf(x0.y, w1.y, fmaf(x0.z, w1.z, fmaf(x0.w, w1.w, a01))));
            a10 = fmaf(x1.x, w0.x, fmaf(x1.y, w0.y, fmaf(x1.z, w0.z, fmaf(x1.w, w0.w, a10))));
            a11 = fmaf(x1.x, w1.x, fmaf(x1.y, w1.y, fmaf(x1.z, w1.z, fmaf(x1.w, w1.w, a11))));
        }
    }

    const float accs[2][2] = {{a00, a01}, {a10, a11}};
#pragma unroll
    for (int dr = 0; dr < 2; ++dr) {
#pragma unroll
        for (int dc = 0; dc < 2; ++dc) {
            const int row = row0 + r0 + dr;
            const int c   = col0 + c0 + dc;
            const float val = accs[dr][dc] + bias[c];
            if (split_heads) {
                const int b = row >> 8, l = row & 255;
                const int h = c >> 6,  d = c & 63;
                out[(size_t)((b * N_HEADS + h) * L_SEQ + l) * DK + d] = val;
            } else {
                out[(size_t)row * 512 + c] = val;
            }
        }
    }
}

// ---------------------------------------------------------------------------
// Fully fused attention middle. One block per (bh, i).
//   scores:  s_j = sum_d q_d * (scale*k_jd + relq_ijd)   [k from L2, relq HBM]
//   softmax over 256 j
//   context: ctx_d = sum_j p_j * (v_jd + relv_ijd)       [v from L2, relv HBM]
// Replaces qk_gemm + attn_rel + pv_gemm: removes 2 launches and the
// s0/p/ctxrel round-trips (~17 MB HBM). relq/relv streaming pattern is the
// same verified per-wave-1KB-contiguous coalescing as before.
// ---------------------------------------------------------------------------
__global__ __launch_bounds__(256) void attn_fused(
    const float* __restrict__ q, const float* __restrict__ k,
    const float* __restrict__ v, const int* __restrict__ mask,
    const float* __restrict__ relq, const float* __restrict__ relv,
    float* __restrict__ ctx)
{
    const int bh = blockIdx.x >> 8;    // 0..15
    const int i  = blockIdx.x & 255;
    const int b  = bh >> 3;
    const int h  = bh & 7;

    const int t    = threadIdx.x;
    const int lane = t & 63;
    const int wave = t >> 6;

    __shared__ float q_s[64];
    __shared__ float sc[256];
    __shared__ float red[8];
    __shared__ float ctxp[4][64];

    if (t < 64) q_s[t] = q[(size_t)(bh * L_SEQ + i) * DK + t];
    __syncthreads();

    const int jgrp = t >> 4;          // 0..15
    const int d0   = (t & 15) << 2;   // 0..60

    const float q0 = q_s[d0], q1 = q_s[d0 + 1], q2 = q_s[d0 + 2], q3 = q_s[d0 + 3];

    const float* relq_row = relq + ((size_t)bh * L_SEQ + i) * L_SEQ * DK;
    const float* k_base   = k + (size_t)bh * L_SEQ * DK;
    const int* mask_row   = mask + (size_t)(b * L_SEQ + i) * L_SEQ;
    const float scale = 0.125f;

    // ---- scores: s_j = sum_d q_d * (scale*k_jd + relq_jd)  (then mask) ----
#pragma unroll 4
    for (int p = 0; p < 16; ++p) {
        const int j = p * 16 + jgrp;
        const float4 rq = *(const float4*)&relq_row[(size_t)j * DK + d0];
        const float4 kv = *(const float4*)&k_base[(size_t)j * DK + d0];
        const float t0 = fmaf(scale, kv.x, rq.x);
        const float t1 = fmaf(scale, kv.y, rq.y);
        const float t2 = fmaf(scale, kv.z, rq.z);
        const float t3 = fmaf(scale, kv.w, rq.w);
        float s = fmaf(q0, t0, fmaf(q1, t1, fmaf(q2, t2, q3 * t3)));
        s += __shfl_xor(s, 1);
        s += __shfl_xor(s, 2);
        s += __shfl_xor(s, 4);
        s += __shfl_xor(s, 8);
        if ((t & 15) == 0) {
            const int m = mask_row[j];
            sc[j] = (m == 0) ? -1e9f : s;
        }
    }
    __syncthreads();

    // ---- softmax over 256 scores ----
    const float s_own = sc[t];
    float mval = s_own;
#pragma unroll
    for (int o = 32; o >= 1; o >>= 1) mval = fmaxf(mval, __shfl_xor(mval, o));
    if (lane == 0) red[wave] = mval;
    __syncthreads();
    mval = fmaxf(fmaxf(red[0], red[1]), fmaxf(red[2], red[3]));

    const float e = __expf(s_own - mval);
    float ssum = e;
#pragma unroll
    for (int o = 32; o >= 1; o >>= 1) ssum += __shfl_xor(ssum, o);
    if (lane == 0) red[4 + wave] = ssum;
    __syncthreads();
    ssum = red[4] + red[5] + red[6] + red[7];

    sc[t] = e / ssum;
    __syncthreads();

    // ---- context: ctx_d = sum_j p_j * (v_jd + relv_jd) ----
    const float* relv_row = relv + ((size_t)bh * L_SEQ + i) * L_SEQ * DK;
    const float* v_base   = v + (size_t)bh * L_SEQ * DK;

    float a0 = 0.f, a1 = 0.f, a2 = 0.f, a3 = 0.f;
#pragma unroll 4
    for (int p = 0; p < 16; ++p) {
        const int j = p * 16 + jgrp;
        const float4 rv = *(const float4*)&relv_row[(size_t)j * DK + d0];
        const float4 vv = *(const float4*)&v_base[(size_t)j * DK + d0];
        const float pw = sc[j];
        a0 = fmaf(pw, rv.x + vv.x, a0);
        a1 = fmaf(pw, rv.y + vv.y, a1);
        a2 = fmaf(pw, rv.z + vv.z, a2);
        a3 = fmaf(pw, rv.w + vv.w, a3);
    }
    a0 += __shfl_xor(a0, 16); a0 += __shfl_xor(a0, 32);
    a1 += __shfl_xor(a1, 16); a1 += __shfl_xor(a1, 32);
    a2 += __shfl_xor(a2, 16); a2 += __shfl_xor(a2, 32);
    a3 += __shfl_xor(a3, 16); a3 += __shfl_xor(a3, 32);
    if (lane < 16) {
        ctxp[wave][lane * 4 + 0] = a0;
        ctxp[wave][lane * 4 + 1] = a1;
        ctxp[wave][lane * 4 + 2] = a2;
        ctxp[wave][lane * 4 + 3] = a3;
    }
    __syncthreads();

    if (t < 64) {
        const float r = ctxp[0][t] + ctxp[1][t] + ctxp[2][t] + ctxp[3][t];
        ctx[(size_t)(b * L_SEQ + i) * D_MODEL + h * DK + t] = r;
    }
}

extern "C" void kernel_launch(void* const* d_in, const int* in_sizes, int n_in,
                              void* d_out, int out_size, void* d_ws, size_t ws_size,
                              hipStream_t stream) {
    const float* query = (const float*)d_in[0];
    const float* key   = (const float*)d_in[1];
    const float* value = (const float*)d_in[2];
    const int*   mask  = (const int*)d_in[3];
    const float* relq  = (const float*)d_in[4];
    const float* relv  = (const float*)d_in[5];
    const float* Wq = (const float*)d_in[6];
    const float* bq = (const float*)d_in[7];
    const float* Wk = (const float*)d_in[8];
    const float* bk = (const float*)d_in[9];
    const float* Wv = (const float*)d_in[10];
    const float* bv = (const float*)d_in[11];
    const float* Wo = (const float*)d_in[12];
    const float* bo = (const float*)d_in[13];
    float* out = (float*)d_out;

    // workspace layout (floats)
    float* ws = (float*)d_ws;
    const size_t QKV = (size_t)BH * L_SEQ * DK;       // 262144 (1 MB each)
    float* q_ws   = ws;
    float* k_ws   = ws + QKV;
    float* v_ws   = ws + 2 * QKV;
    float* ctx_ws = ws + 3 * QKV;                     // total 4 MB

    proj_gemm<<<dim3(16, 16, 3), 256, 0, stream>>>(
        query, key, value, Wq, Wk, Wv, bq, bk, bv, q_ws, k_ws, v_ws, 1);

    attn_fused<<<BH * L_SEQ, 256, 0, stream>>>(q_ws, k_ws, v_ws, mask,
                                               relq, relv, ctx_ws);

    proj_gemm<<<dim3(16, 16, 1), 256, 0, stream>>>(
        ctx_ws, ctx_ws, ctx_ws, Wo, Wo, Wo, bo, bo, bo, out, out, out, 0);
}

// Round 2
// 566.100 us; speedup vs baseline: 1.0344x; 1.0344x over previous
//
#include <hip/hip_runtime.h>

// Problem constants: B=2, L=256, D=512, H=8, dk=64
#define L_SEQ 256
#define D_MODEL 512
#define N_HEADS 8
#define DK 64
#define N_BATCH 2
#define BH (N_BATCH * N_HEADS)   // 16
#define ROWS 4                   // attn rows per block

// ---------------------------------------------------------------------------
// NT GEMM for the 512x512(x512) projections. out[r,c] = X[r,:].W[c,:] + bias[c]
// v2: K-step 64 (half the barriers), LDS pad 72 (reads stay <=2-way),
// register-prefetch double buffer so global latency hides under compute —
// matters most for the out-proj which runs at 1 block/CU.
// ---------------------------------------------------------------------------
__global__ __launch_bounds__(256) void proj_gemm(
    const float* __restrict__ X0, const float* __restrict__ X1, const float* __restrict__ X2,
    const float* __restrict__ W0, const float* __restrict__ W1, const float* __restrict__ W2,
    const float* __restrict__ B0, const float* __restrict__ B1, const float* __restrict__ B2,
    float* __restrict__ O0, float* __restrict__ O1, float* __restrict__ O2,
    int split_heads)
{
    const int z = blockIdx.z;
    const float* X    = (z == 0) ? X0 : (z == 1) ? X1 : X2;
    const float* W    = (z == 0) ? W0 : (z == 1) ? W1 : W2;
    const float* bias = (z == 0) ? B0 : (z == 1) ? B1 : B2;
    float* out        = (z == 0) ? O0 : (z == 1) ? O1 : O2;

    __shared__ float Xs[32][72];
    __shared__ float Ws[32][72];

    const int t = threadIdx.x;
    const int row0 = blockIdx.x * 32;
    const int col0 = blockIdx.y * 32;
    const int lr = t >> 3;          // 0..31 (staging row)
    const int lc = (t & 7) << 3;    // 0..56 (staging col, 2x float4)
    const int r0 = (t >> 4) * 2;    // output rows r0, r0+1
    const int c0 = (t & 15) * 2;    // output cols c0, c0+1

    const float* Xrow = X + (size_t)(row0 + lr) * 512 + lc;
    const float* Wrow = W + (size_t)(col0 + lr) * 512 + lc;

    // prefetch k0=0 tile into registers
    float4 cX0 = *(const float4*)&Xrow[0];
    float4 cX1 = *(const float4*)&Xrow[4];
    float4 cW0 = *(const float4*)&Wrow[0];
    float4 cW1 = *(const float4*)&Wrow[4];

    float a00 = 0.f, a01 = 0.f, a10 = 0.f, a11 = 0.f;

    for (int k0 = 0; k0 < 512; k0 += 64) {
        __syncthreads();
        *(float4*)&Xs[lr][lc]     = cX0;
        *(float4*)&Xs[lr][lc + 4] = cX1;
        *(float4*)&Ws[lr][lc]     = cW0;
        *(float4*)&Ws[lr][lc + 4] = cW1;
        __syncthreads();
        if (k0 + 64 < 512) {   // prefetch next tile; latency hides under compute
            cX0 = *(const float4*)&Xrow[k0 + 64];
            cX1 = *(const float4*)&Xrow[k0 + 68];
            cW0 = *(const float4*)&Wrow[k0 + 64];
            cW1 = *(const float4*)&Wrow[k0 + 68];
        }
#pragma unroll
        for (int kk = 0; kk < 64; kk += 4) {
            const float4 x0 = *(const float4*)&Xs[r0][kk];
            const float4 x1 = *(const float4*)&Xs[r0 + 1][kk];
            const float4 w0 = *(const float4*)&Ws[c0][kk];
            const float4 w1 = *(const float4*)&Ws[c0 + 1][kk];
            a00 = fmaf(x0.x, w0.x, fmaf(x0.y, w0.y, fmaf(x0.z, w0.z, fmaf(x0.w, w0.w, a00))));
            a01 = fmaf(x0.x, w1.x, fmaf(x0.y, w1.y, fmaf(x0.z, w1.z, fmaf(x0.w, w1.w, a01))));
            a10 = fmaf(x1.x, w0.x, fmaf(x1.y, w0.y, fmaf(x1.z, w0.z, fmaf(x1.w, w0.w, a10))));
            a11 = fmaf(x1.x, w1.x, fmaf(x1.y, w1.y, fmaf(x1.z, w1.z, fmaf(x1.w, w1.w, a11))));
        }
    }

    const float accs[2][2] = {{a00, a01}, {a10, a11}};
#pragma unroll
    for (int dr = 0; dr < 2; ++dr) {
#pragma unroll
        for (int dc = 0; dc < 2; ++dc) {
            const int row = row0 + r0 + dr;
            const int c   = col0 + c0 + dc;
            const float val = accs[dr][dc] + bias[c];
            if (split_heads) {
                const int b = row >> 8, l = row & 255;
                const int h = c >> 6,  d = c & 63;
                out[(size_t)((b * N_HEADS + h) * L_SEQ + l) * DK + d] = val;
            } else {
                out[(size_t)row * 512 + c] = val;
            }
        }
    }
}

// ---------------------------------------------------------------------------
// Fused attention middle, ROWS=4 rows of one (bh) per block.
// k/v tiles are read ONCE per block and amortized over 4 rows: VMEM bytes
// drop from 1049 MB (R1: at the ~10.6 B/cyc/CU ceiling) to 665 MB.
//   scores:  s_rj = sum_d q_rd * (scale*k_jd + relq_r_jd)
//   softmax (mask folded in here, not in the stream loop)
//   context: ctx_rd = sum_j p_rj * (v_jd + relv_r_jd)
// Grid 16*64 = 1024 blocks = 4/CU uniform. All global streams stay in the
// verified coalesced jgrp/d0 layout (1 KB contiguous per wave instruction).
// ---------------------------------------------------------------------------
__global__ __launch_bounds__(256) void attn_fused(
    const float* __restrict__ q, const float* __restrict__ k,
    const float* __restrict__ v, const int* __restrict__ mask,
    const float* __restrict__ relq, const float* __restrict__ relv,
    float* __restrict__ ctx)
{
    const int bh = blockIdx.x >> 6;          // 0..15
    const int i0 = (blockIdx.x & 63) * ROWS; // 0..252
    const int b  = bh >> 3;
    const int h  = bh & 7;

    const int t    = threadIdx.x;
    const int lane = t & 63;
    const int wave = t >> 6;

    __shared__ float q_s[ROWS][64];
    __shared__ float sc[ROWS][256];
    __shared__ float red[2][ROWS][4];
    __shared__ float ctxp[ROWS][4][64];

    {   // stage q rows i0..i0+3 (coalesced 1 KB)
        const int r = t >> 6, d = t & 63;
        q_s[r][d] = q[((size_t)bh * L_SEQ + i0 + r) * DK + d];
    }
    __syncthreads();

    const int jgrp = t >> 4;          // 0..15
    const int d0   = (t & 15) << 2;   // 0..60

    float4 qr[ROWS];
#pragma unroll
    for (int r = 0; r < ROWS; ++r) qr[r] = *(const float4*)&q_s[r][d0];

    const float* kb = k + (size_t)bh * L_SEQ * DK;
    const float* vb = v + (size_t)bh * L_SEQ * DK;
    const size_t relbase = ((size_t)bh * L_SEQ + i0) * L_SEQ * DK;
    const float scale = 0.125f;

    // ---- scores ----
#pragma unroll 2
    for (int p = 0; p < 16; ++p) {
        const int j = p * 16 + jgrp;
        const float4 kv = *(const float4*)&kb[(size_t)j * DK + d0];
        float4 rq[ROWS];
#pragma unroll
        for (int r = 0; r < ROWS; ++r)
            rq[r] = *(const float4*)&relq[relbase + ((size_t)r * L_SEQ + j) * DK + d0];
#pragma unroll
        for (int r = 0; r < ROWS; ++r) {
            const float t0 = fmaf(scale, kv.x, rq[r].x);
            const float t1 = fmaf(scale, kv.y, rq[r].y);
            const float t2 = fmaf(scale, kv.z, rq[r].z);
            const float t3 = fmaf(scale, kv.w, rq[r].w);
            float s = fmaf(qr[r].x, t0, fmaf(qr[r].y, t1, fmaf(qr[r].z, t2, qr[r].w * t3)));
            s += __shfl_xor(s, 1);
            s += __shfl_xor(s, 2);
            s += __shfl_xor(s, 4);
            s += __shfl_xor(s, 8);
            if ((t & 15) == 0) sc[r][j] = s;
        }
    }
    __syncthreads();

    // ---- softmax over 256 scores, 4 rows in parallel; mask applied here ----
    const int* mb = mask + (size_t)b * L_SEQ * L_SEQ + (size_t)i0 * L_SEQ;
    float sraw[ROWS], e[ROWS];
#pragma unroll
    for (int r = 0; r < ROWS; ++r) {
        const int mk = mb[(size_t)r * L_SEQ + t];
        sraw[r] = (mk == 0) ? -1e9f : sc[r][t];
    }
    {
        float mv[ROWS];
#pragma unroll
        for (int r = 0; r < ROWS; ++r) mv[r] = sraw[r];
#pragma unroll
        for (int o = 32; o >= 1; o >>= 1)
#pragma unroll
            for (int r = 0; r < ROWS; ++r) mv[r] = fmaxf(mv[r], __shfl_xor(mv[r], o));
        if (lane == 0)
#pragma unroll
            for (int r = 0; r < ROWS; ++r) red[0][r][wave] = mv[r];
    }
    __syncthreads();
#pragma unroll
    for (int r = 0; r < ROWS; ++r) {
        const float M = fmaxf(fmaxf(red[0][r][0], red[0][r][1]),
                              fmaxf(red[0][r][2], red[0][r][3]));
        e[r] = __expf(sraw[r] - M);
    }
    {
        float sm[ROWS];
#pragma unroll
        for (int r = 0; r < ROWS; ++r) sm[r] = e[r];
#pragma unroll
        for (int o = 32; o >= 1; o >>= 1)
#pragma unroll
            for (int r = 0; r < ROWS; ++r) sm[r] += __shfl_xor(sm[r], o);
        if (lane == 0)
#pragma unroll
            for (int r = 0; r < ROWS; ++r) red[1][r][wave] = sm[r];
    }
    __syncthreads();
#pragma unroll
    for (int r = 0; r < ROWS; ++r) {
        const float S = red[1][r][0] + red[1][r][1] + red[1][r][2] + red[1][r][3];
        sc[r][t] = e[r] / S;
    }
    __syncthreads();

    // ---- context: ctx_rd = sum_j p_rj * (v_jd + relv_r_jd) ----
    float4 acc[ROWS];
#pragma unroll
    for (int r = 0; r < ROWS; ++r) acc[r] = make_float4(0.f, 0.f, 0.f, 0.f);

#pragma unroll 2
    for (int p = 0; p < 16; ++p) {
        const int j = p * 16 + jgrp;
        const float4 vv = *(const float4*)&vb[(size_t)j * DK + d0];
        float4 rv[ROWS];
#pragma unroll
        for (int r = 0; r < ROWS; ++r)
            rv[r] = *(const float4*)&relv[relbase + ((size_t)r * L_SEQ + j) * DK + d0];
#pragma unroll
        for (int r = 0; r < ROWS; ++r) {
            const float pw = sc[r][j];
            acc[r].x = fmaf(pw, vv.x + rv[r].x, acc[r].x);
            acc[r].y = fmaf(pw, vv.y + rv[r].y, acc[r].y);
            acc[r].z = fmaf(pw, vv.z + rv[r].z, acc[r].z);
            acc[r].w = fmaf(pw, vv.w + rv[r].w, acc[r].w);
        }
    }
#pragma unroll
    for (int r = 0; r < ROWS; ++r) {
        acc[r].x += __shfl_xor(acc[r].x, 16); acc[r].x += __shfl_xor(acc[r].x, 32);
        acc[r].y += __shfl_xor(acc[r].y, 16); acc[r].y += __shfl_xor(acc[r].y, 32);
        acc[r].z += __shfl_xor(acc[r].z, 16); acc[r].z += __shfl_xor(acc[r].z, 32);
        acc[r].w += __shfl_xor(acc[r].w, 16); acc[r].w += __shfl_xor(acc[r].w, 32);
        if (lane < 16) {
            ctxp[r][wave][lane * 4 + 0] = acc[r].x;
            ctxp[r][wave][lane * 4 + 1] = acc[r].y;
            ctxp[r][wave][lane * 4 + 2] = acc[r].z;
            ctxp[r][wave][lane * 4 + 3] = acc[r].w;
        }
    }
    __syncthreads();

    {   // write 4 rows, one per 64-thread group (coalesced 256 B per row)
        const int r = t >> 6, d = t & 63;
        const float o = ctxp[r][0][d] + ctxp[r][1][d] + ctxp[r][2][d] + ctxp[r][3][d];
        ctx[((size_t)b * L_SEQ + i0 + r) * D_MODEL + h * DK + d] = o;
    }
}

extern "C" void kernel_launch(void* const* d_in, const int* in_sizes, int n_in,
                              void* d_out, int out_size, void* d_ws, size_t ws_size,
                              hipStream_t stream) {
    const float* query = (const float*)d_in[0];
    const float* key   = (const float*)d_in[1];
    const float* value = (const float*)d_in[2];
    const int*   mask  = (const int*)d_in[3];
    const float* relq  = (const float*)d_in[4];
    const float* relv  = (const float*)d_in[5];
    const float* Wq = (const float*)d_in[6];
    const float* bq = (const float*)d_in[7];
    const float* Wk = (const float*)d_in[8];
    const float* bk = (const float*)d_in[9];
    const float* Wv = (const float*)d_in[10];
    const float* bv = (const float*)d_in[11];
    const float* Wo = (const float*)d_in[12];
    const float* bo = (const float*)d_in[13];
    float* out = (float*)d_out;

    // workspace layout (floats)
    float* ws = (float*)d_ws;
    const size_t QKV = (size_t)BH * L_SEQ * DK;       // 262144 (1 MB each)
    float* q_ws   = ws;
    float* k_ws   = ws + QKV;
    float* v_ws   = ws + 2 * QKV;
    float* ctx_ws = ws + 3 * QKV;                     // total 4 MB

    proj_gemm<<<dim3(16, 16, 3), 256, 0, stream>>>(
        query, key, value, Wq, Wk, Wv, bq, bk, bv, q_ws, k_ws, v_ws, 1);

    attn_fused<<<BH * (L_SEQ / ROWS), 256, 0, stream>>>(q_ws, k_ws, v_ws, mask,
                                                        relq, relv, ctx_ws);

    proj_gemm<<<dim3(16, 16, 1), 256, 0, stream>>>(
        ctx_ws, ctx_ws, ctx_ws, Wo, Wo, Wo, bo, bo, bo, out, out, out, 0);
}

// Round 4
// 555.716 us; speedup vs baseline: 1.0537x; 1.0187x over previous
//
#include <hip/hip_runtime.h>

// Problem constants: B=2, L=256, D=512, H=8, dk=64
#define L_SEQ 256
#define D_MODEL 512
#define N_HEADS 8
#define DK 64
#define N_BATCH 2
#define BH (N_BATCH * N_HEADS)   // 16
#define ROWS 4                   // attn rows per block

// ---------------------------------------------------------------------------
// NT GEMM for the 512x512(x512) projections. out[r,c] = X[r,:].W[c,:] + bias[c]
// v3: XOR swizzle ((row>>1)&7)<<2 on the LDS column for BOTH tiles.
// R2's Ws read was an 8-way bank conflict (16 c-rows x stride-72 -> 2 bank
// quads); swizzle spreads the 16 lanes over 8 quads -> 2-way (free, m136).
// Swizzle is 4-aligned so float4 reads stay 16B-aligned and FP order is
// bit-identical. K-step 64, register-prefetch double buffer kept.
// ---------------------------------------------------------------------------
__global__ __launch_bounds__(256) void proj_gemm(
    const float* __restrict__ X0, const float* __restrict__ X1, const float* __restrict__ X2,
    const float* __restrict__ W0, const float* __restrict__ W1, const float* __restrict__ W2,
    const float* __restrict__ B0, const float* __restrict__ B1, const float* __restrict__ B2,
    float* __restrict__ O0, float* __restrict__ O1, float* __restrict__ O2,
    int split_heads)
{
    const int z = blockIdx.z;
    const float* X    = (z == 0) ? X0 : (z == 1) ? X1 : X2;
    const float* W    = (z == 0) ? W0 : (z == 1) ? W1 : W2;
    const float* bias = (z == 0) ? B0 : (z == 1) ? B1 : B2;
    float* out        = (z == 0) ? O0 : (z == 1) ? O1 : O2;

    __shared__ float Xs[32][72];
    __shared__ float Ws[32][72];

    const int t = threadIdx.x;
    const int row0 = blockIdx.x * 32;
    const int col0 = blockIdx.y * 32;
    const int lr = t >> 3;          // 0..31 (staging row)
    const int lc = (t & 7) << 3;    // 0..56 (staging col, 2x float4)
    const int r0 = (t >> 4) * 2;    // output rows r0, r0+1
    const int c0 = (t & 15) * 2;    // output cols c0, c0+1

    const int swl = ((lr >> 1) & 7) << 2;   // stage-write swizzle
    const int swx = ((r0 >> 1) & 7) << 2;   // x-read swizzle (same for r0,r0+1)
    const int swc = ((c0 >> 1) & 7) << 2;   // w-read swizzle (same for c0,c0+1)

    const float* Xrow = X + (size_t)(row0 + lr) * 512 + lc;
    const float* Wrow = W + (size_t)(col0 + lr) * 512 + lc;

    // prefetch k0=0 tile into registers
    float4 cX0 = *(const float4*)&Xrow[0];
    float4 cX1 = *(const float4*)&Xrow[4];
    float4 cW0 = *(const float4*)&Wrow[0];
    float4 cW1 = *(const float4*)&Wrow[4];

    float a00 = 0.f, a01 = 0.f, a10 = 0.f, a11 = 0.f;

    for (int k0 = 0; k0 < 512; k0 += 64) {
        __syncthreads();
        *(float4*)&Xs[lr][lc ^ swl]       = cX0;
        *(float4*)&Xs[lr][(lc + 4) ^ swl] = cX1;
        *(float4*)&Ws[lr][lc ^ swl]       = cW0;
        *(float4*)&Ws[lr][(lc + 4) ^ swl] = cW1;
        __syncthreads();
        if (k0 + 64 < 512) {   // prefetch next tile; latency hides under compute
            cX0 = *(const float4*)&Xrow[k0 + 64];
            cX1 = *(const float4*)&Xrow[k0 + 68];
            cW0 = *(const float4*)&Wrow[k0 + 64];
            cW1 = *(const float4*)&Wrow[k0 + 68];
        }
#pragma unroll
        for (int kk = 0; kk < 64; kk += 4) {
            const float4 x0 = *(const float4*)&Xs[r0][kk ^ swx];
            const float4 x1 = *(const float4*)&Xs[r0 + 1][kk ^ swx];
            const float4 w0 = *(const float4*)&Ws[c0][kk ^ swc];
            const float4 w1 = *(const float4*)&Ws[c0 + 1][kk ^ swc];
            a00 = fmaf(x0.x, w0.x, fmaf(x0.y, w0.y, fmaf(x0.z, w0.z, fmaf(x0.w, w0.w, a00))));
            a01 = fmaf(x0.x, w1.x, fmaf(x0.y, w1.y, fmaf(x0.z, w1.z, fmaf(x0.w, w1.w, a01))));
            a10 = fmaf(x1.x, w0.x, fmaf(x1.y, w0.y, fmaf(x1.z, w0.z, fmaf(x1.w, w0.w, a10))));
            a11 = fmaf(x1.x, w1.x, fmaf(x1.y, w1.y, fmaf(x1.z, w1.z, fmaf(x1.w, w1.w, a11))));
        }
    }

    const float accs[2][2] = {{a00, a01}, {a10, a11}};
#pragma unroll
    for (int dr = 0; dr < 2; ++dr) {
#pragma unroll
        for (int dc = 0; dc < 2; ++dc) {
            const int row = row0 + r0 + dr;
            const int c   = col0 + c0 + dc;
            const float val = accs[dr][dc] + bias[c];
            if (split_heads) {
                const int b = row >> 8, l = row & 255;
                const int h = c >> 6,  d = c & 63;
                out[(size_t)((b * N_HEADS + h) * L_SEQ + l) * DK + d] = val;
            } else {
                out[(size_t)row * 512 + c] = val;
            }
        }
    }
}

// ---------------------------------------------------------------------------
// Fused attention middle, ROWS=4 rows of one (bh) per block.
// k/v tiles are read ONCE per block and amortized over 4 rows (665 MB total
// VMEM vs 1049 in R1). v4: stream loops unrolled 4 (20 b128 in flight) to
// cover HBM latency at 16 waves/CU.
// ---------------------------------------------------------------------------
__global__ __launch_bounds__(256) void attn_fused(
    const float* __restrict__ q, const float* __restrict__ k,
    const float* __restrict__ v, const int* __restrict__ mask,
    const float* __restrict__ relq, const float* __restrict__ relv,
    float* __restrict__ ctx)
{
    const int bh = blockIdx.x >> 6;          // 0..15
    const int i0 = (blockIdx.x & 63) * ROWS; // 0..252
    const int b  = bh >> 3;
    const int h  = bh & 7;

    const int t    = threadIdx.x;
    const int lane = t & 63;
    const int wave = t >> 6;

    __shared__ float q_s[ROWS][64];
    __shared__ float sc[ROWS][256];
    __shared__ float red[2][ROWS][4];
    __shared__ float ctxp[ROWS][4][64];

    {   // stage q rows i0..i0+3 (coalesced 1 KB)
        const int r = t >> 6, d = t & 63;
        q_s[r][d] = q[((size_t)bh * L_SEQ + i0 + r) * DK + d];
    }
    __syncthreads();

    const int jgrp = t >> 4;          // 0..15
    const int d0   = (t & 15) << 2;   // 0..60

    float4 qr[ROWS];
#pragma unroll
    for (int r = 0; r < ROWS; ++r) qr[r] = *(const float4*)&q_s[r][d0];

    const float* kb = k + (size_t)bh * L_SEQ * DK;
    const float* vb = v + (size_t)bh * L_SEQ * DK;
    const size_t relbase = ((size_t)bh * L_SEQ + i0) * L_SEQ * DK;
    const float scale = 0.125f;

    // ---- scores ----
#pragma unroll 4
    for (int p = 0; p < 16; ++p) {
        const int j = p * 16 + jgrp;
        const float4 kv = *(const float4*)&kb[(size_t)j * DK + d0];
        float4 rq[ROWS];
#pragma unroll
        for (int r = 0; r < ROWS; ++r)
            rq[r] = *(const float4*)&relq[relbase + ((size_t)r * L_SEQ + j) * DK + d0];
#pragma unroll
        for (int r = 0; r < ROWS; ++r) {
            const float t0 = fmaf(scale, kv.x, rq[r].x);
            const float t1 = fmaf(scale, kv.y, rq[r].y);
            const float t2 = fmaf(scale, kv.z, rq[r].z);
            const float t3 = fmaf(scale, kv.w, rq[r].w);
            float s = fmaf(qr[r].x, t0, fmaf(qr[r].y, t1, fmaf(qr[r].z, t2, qr[r].w * t3)));
            s += __shfl_xor(s, 1);
            s += __shfl_xor(s, 2);
            s += __shfl_xor(s, 4);
            s += __shfl_xor(s, 8);
            if ((t & 15) == 0) sc[r][j] = s;
        }
    }
    __syncthreads();

    // ---- softmax over 256 scores, 4 rows in parallel; mask applied here ----
    const int* mb = mask + (size_t)b * L_SEQ * L_SEQ + (size_t)i0 * L_SEQ;
    float sraw[ROWS], e[ROWS];
#pragma unroll
    for (int r = 0; r < ROWS; ++r) {
        const int mk = mb[(size_t)r * L_SEQ + t];
        sraw[r] = (mk == 0) ? -1e9f : sc[r][t];
    }
    {
        float mv[ROWS];
#pragma unroll
        for (int r = 0; r < ROWS; ++r) mv[r] = sraw[r];
#pragma unroll
        for (int o = 32; o >= 1; o >>= 1)
#pragma unroll
            for (int r = 0; r < ROWS; ++r) mv[r] = fmaxf(mv[r], __shfl_xor(mv[r], o));
        if (lane == 0)
#pragma unroll
            for (int r = 0; r < ROWS; ++r) red[0][r][wave] = mv[r];
    }
    __syncthreads();
#pragma unroll
    for (int r = 0; r < ROWS; ++r) {
        const float M = fmaxf(fmaxf(red[0][r][0], red[0][r][1]),
                              fmaxf(red[0][r][2], red[0][r][3]));
        e[r] = __expf(sraw[r] - M);
    }
    {
        float sm[ROWS];
#pragma unroll
        for (int r = 0; r < ROWS; ++r) sm[r] = e[r];
#pragma unroll
        for (int o = 32; o >= 1; o >>= 1)
#pragma unroll
            for (int r = 0; r < ROWS; ++r) sm[r] += __shfl_xor(sm[r], o);
        if (lane == 0)
#pragma unroll
            for (int r = 0; r < ROWS; ++r) red[1][r][wave] = sm[r];
    }
    __syncthreads();
#pragma unroll
    for (int r = 0; r < ROWS; ++r) {
        const float S = red[1][r][0] + red[1][r][1] + red[1][r][2] + red[1][r][3];
        sc[r][t] = e[r] / S;
    }
    __syncthreads();

    // ---- context: ctx_rd = sum_j p_rj * (v_jd + relv_r_jd) ----
    float4 acc[ROWS];
#pragma unroll
    for (int r = 0; r < ROWS; ++r) acc[r] = make_float4(0.f, 0.f, 0.f, 0.f);

#pragma unroll 4
    for (int p = 0; p < 16; ++p) {
        const int j = p * 16 + jgrp;
        const float4 vv = *(const float4*)&vb[(size_t)j * DK + d0];
        float4 rv[ROWS];
#pragma unroll
        for (int r = 0; r < ROWS; ++r)
            rv[r] = *(const float4*)&relv[relbase + ((size_t)r * L_SEQ + j) * DK + d0];
#pragma unroll
        for (int r = 0; r < ROWS; ++r) {
            const float pw = sc[r][j];
            acc[r].x = fmaf(pw, vv.x + rv[r].x, acc[r].x);
            acc[r].y = fmaf(pw, vv.y + rv[r].y, acc[r].y);
            acc[r].z = fmaf(pw, vv.z + rv[r].z, acc[r].z);
            acc[r].w = fmaf(pw, vv.w + rv[r].w, acc[r].w);
        }
    }
#pragma unroll
    for (int r = 0; r < ROWS; ++r) {
        acc[r].x += __shfl_xor(acc[r].x, 16); acc[r].x += __shfl_xor(acc[r].x, 32);
        acc[r].y += __shfl_xor(acc[r].y, 16); acc[r].y += __shfl_xor(acc[r].y, 32);
        acc[r].z += __shfl_xor(acc[r].z, 16); acc[r].z += __shfl_xor(acc[r].z, 32);
        acc[r].w += __shfl_xor(acc[r].w, 16); acc[r].w += __shfl_xor(acc[r].w, 32);
        if (lane < 16) {
            ctxp[r][wave][lane * 4 + 0] = acc[r].x;
            ctxp[r][wave][lane * 4 + 1] = acc[r].y;
            ctxp[r][wave][lane * 4 + 2] = acc[r].z;
            ctxp[r][wave][lane * 4 + 3] = acc[r].w;
        }
    }
    __syncthreads();

    {   // write 4 rows, one per 64-thread group (coalesced 256 B per row)
        const int r = t >> 6, d = t & 63;
        const float o = ctxp[r][0][d] + ctxp[r][1][d] + ctxp[r][2][d] + ctxp[r][3][d];
        ctx[((size_t)b * L_SEQ + i0 + r) * D_MODEL + h * DK + d] = o;
    }
}

extern "C" void kernel_launch(void* const* d_in, const int* in_sizes, int n_in,
                              void* d_out, int out_size, void* d_ws, size_t ws_size,
                              hipStream_t stream) {
    const float* query = (const float*)d_in[0];
    const float* key   = (const float*)d_in[1];
    const float* value = (const float*)d_in[2];
    const int*   mask  = (const int*)d_in[3];
    const float* relq  = (const float*)d_in[4];
    const float* relv  = (const float*)d_in[5];
    const float* Wq = (const float*)d_in[6];
    const float* bq = (const float*)d_in[7];
    const float* Wk = (const float*)d_in[8];
    const float* bk = (const float*)d_in[9];
    const float* Wv = (const float*)d_in[10];
    const float* bv = (const float*)d_in[11];
    const float* Wo = (const float*)d_in[12];
    const float* bo = (const float*)d_in[13];
    float* out = (float*)d_out;

    // workspace layout (floats)
    float* ws = (float*)d_ws;
    const size_t QKV = (size_t)BH * L_SEQ * DK;       // 262144 (1 MB each)
    float* q_ws   = ws;
    float* k_ws   = ws + QKV;
    float* v_ws   = ws + 2 * QKV;
    float* ctx_ws = ws + 3 * QKV;                     // total 4 MB

    proj_gemm<<<dim3(16, 16, 3), 256, 0, stream>>>(
        query, key, value, Wq, Wk, Wv, bq, bk, bv, q_ws, k_ws, v_ws, 1);

    attn_fused<<<BH * (L_SEQ / ROWS), 256, 0, stream>>>(q_ws, k_ws, v_ws, mask,
                                                        relq, relv, ctx_ws);

    proj_gemm<<<dim3(16, 16, 1), 256, 0, stream>>>(
        ctx_ws, ctx_ws, ctx_ws, Wo, Wo, Wo, bo, bo, bo, out, out, out, 0);
}